// Round 6
// baseline (458.017 us; speedup 1.0000x reference)
//
#include <hip/hip_runtime.h>

#define D 128

typedef short bfrag __attribute__((ext_vector_type(8)));      // 8 bf16 = 4 VGPRs
typedef float f32x4 __attribute__((ext_vector_type(4)));
typedef unsigned uint32;

// ---------------- bf16 split helpers ----------------
__device__ inline unsigned short bf16_rne(float x) {
    unsigned u = __float_as_uint(x);
    return (unsigned short)((u + 0x7FFFu + ((u >> 16) & 1u)) >> 16);
}
__device__ inline float bf16_to_f(unsigned short h) {
    return __uint_as_float(((unsigned)h) << 16);
}
// pair word: hi in bits [15:0], lo in bits [31:16]
__device__ inline unsigned split2p(float x) {
    unsigned short hi = bf16_rne(x);
    unsigned short lo = bf16_rne(x - bf16_to_f(hi));
    return (unsigned)hi | ((unsigned)lo << 16);
}

// unpack 8 pair-words (32B) -> ah (8 hi bf16), al (8 lo bf16)
__device__ inline void unpair(const uint32* __restrict__ p, bfrag& ah, bfrag& al) {
    uint4 q0 = *(const uint4*)p;
    uint4 q1 = *(const uint4*)(p + 4);
    union { uint32 u[4]; bfrag b; } H, L;
    H.u[0] = __builtin_amdgcn_perm(q0.y, q0.x, 0x05040100u);
    H.u[1] = __builtin_amdgcn_perm(q0.w, q0.z, 0x05040100u);
    H.u[2] = __builtin_amdgcn_perm(q1.y, q1.x, 0x05040100u);
    H.u[3] = __builtin_amdgcn_perm(q1.w, q1.z, 0x05040100u);
    L.u[0] = __builtin_amdgcn_perm(q0.y, q0.x, 0x07060302u);
    L.u[1] = __builtin_amdgcn_perm(q0.w, q0.z, 0x07060302u);
    L.u[2] = __builtin_amdgcn_perm(q1.y, q1.x, 0x07060302u);
    L.u[3] = __builtin_amdgcn_perm(q1.w, q1.z, 0x07060302u);
    ah = H.b;
    al = L.b;
}

// ---------------- edge dtype detection (+ deg zero) ----------------
__global__ __launch_bounds__(256) void detect_mode(const int* __restrict__ e, int* __restrict__ mode,
                                                   int* __restrict__ deg, int E, int N) {
    int gid = blockIdx.x * 256 + threadIdx.x;
    int stride = gridDim.x * 256;
    for (int i = gid; i < N; i += stride) deg[i] = 0;
    int found = 0;
    for (int p = gid; p < E; p += stride)
        if (e[2 * p + 1] != 0) found = 1;
    if (found) atomicOr(mode, 1);   // 1 => int32, 0 => int64
}

__global__ __launch_bounds__(256) void repack_edges(const void* __restrict__ eraw, const int* __restrict__ mode,
                                                    int* __restrict__ out, int n2) {
    int i = blockIdx.x * 256 + threadIdx.x;
    if (i >= n2) return;
    int m = *mode;
    out[i] = m ? ((const int*)eraw)[i] : (int)((const long long*)eraw)[i];
}

// ---------------- degree ----------------
__global__ __launch_bounds__(256) void compute_deg(const int* __restrict__ dst, int* __restrict__ deg, int E) {
    int i = blockIdx.x * 256 + threadIdx.x;
    if (i < E) atomicAdd(&deg[dst[i]], 1);
}

// dinv + rowbeg (atomic bump allocator; ordering across nodes irrelevant) + cursor zero
__global__ __launch_bounds__(256) void node_offsets(const int* __restrict__ deg, float* __restrict__ dinv,
                                                    int* __restrict__ rowbeg, int* __restrict__ cursor,
                                                    int* __restrict__ counter, int N) {
    int i = blockIdx.x * 256 + threadIdx.x;
    if (i >= N) return;
    int d = deg[i];
    dinv[i] = 1.0f / sqrtf((float)(d + 1));   // +1 self-loop
    rowbeg[i] = atomicAdd(counter, d);
    cursor[i] = 0;
}

// ---------------- CSR fill (counting sort by dst) ----------------
__global__ __launch_bounds__(256) void fill_csr(const int* __restrict__ src, const int* __restrict__ dst,
                                                const int* __restrict__ rowbeg, int* __restrict__ cursor,
                                                int* __restrict__ csr_src, int E) {
    int e = blockIdx.x * 256 + threadIdx.x;
    if (e >= E) return;
    int d = dst[e];
    int pos = atomicAdd(&cursor[d], 1);
    csr_src[rowbeg[d] + pos] = src[e];
}

// ---------------- fp32 -> pair plane (whole matrix) ----------------
__global__ __launch_bounds__(256) void split_matrix(const float* __restrict__ in, uint32* __restrict__ P, int n4) {
    int i = blockIdx.x * 256 + threadIdx.x;
    if (i >= n4) return;
    float4 v = ((const float4*)in)[i];
    uint4 p;
    p.x = split2p(v.x); p.y = split2p(v.y); p.z = split2p(v.z); p.w = split2p(v.w);
    ((uint4*)P)[i] = p;
}

// ---------------- all weights: transpose + split (4 matrices, one dispatch) ----------------
__global__ __launch_bounds__(256) void prep_w_all(const float* __restrict__ Wpre, const float* __restrict__ W1,
                                                  const float* __restrict__ W2, const float* __restrict__ Wpost,
                                                  unsigned short* __restrict__ preh, unsigned short* __restrict__ prel,
                                                  unsigned short* __restrict__ w1h, unsigned short* __restrict__ w1l,
                                                  unsigned short* __restrict__ w2h, unsigned short* __restrict__ w2l,
                                                  unsigned short* __restrict__ poh, unsigned short* __restrict__ pol) {
    int i = blockIdx.x * 256 + threadIdx.x;
    const float* W; unsigned short *wh, *wl; int idx, ncols;
    if (i < 16384)      { W = Wpre;  wh = preh; wl = prel; idx = i;         ncols = 128; }
    else if (i < 32768) { W = W1;    wh = w1h;  wl = w1l;  idx = i - 16384; ncols = 128; }
    else if (i < 49152) { W = W2;    wh = w2h;  wl = w2l;  idx = i - 32768; ncols = 128; }
    else if (i < 55296) { W = Wpost; wh = poh;  wl = pol;  idx = i - 49152; ncols = 40;  }
    else return;
    int n = idx >> 7, k = idx & 127;
    float v = (n < ncols) ? W[k * ncols + n] : 0.f;
    unsigned p = split2p(v);
    wh[idx] = (unsigned short)p;
    wl[idx] = (unsigned short)(p >> 16);
}

// ---------------- bf16x3 MFMA GEMM (A from pair plane) ----------------
// EPI=0: Cf fp32 [N][D].  EPI=1: bias -> pair plane Pout.  EPI=2: bias + fp32, col<outW mask.
template<int NTILES, int EPI>
__global__ __launch_bounds__(256) void gemm_mfma(const uint32* __restrict__ P,
                                                 const unsigned short* __restrict__ Wth,
                                                 const unsigned short* __restrict__ Wtl,
                                                 const float* __restrict__ bias,
                                                 float* __restrict__ Cf,
                                                 uint32* __restrict__ Pout,
                                                 int nStrips, int N, int outW) {
    int wave = threadIdx.x >> 6;
    int lane = threadIdx.x & 63;
    int l15 = lane & 15, lg = lane >> 4;
    int colbase = blockIdx.y * 64;

    // persistent B fragments: wt[col][k] contiguous in k -> 16B per lane
    bfrag wh[4][NTILES], wl[4][NTILES];
    #pragma unroll
    for (int ks = 0; ks < 4; ks++)
        #pragma unroll
        for (int nt = 0; nt < NTILES; nt++) {
            size_t off = (size_t)(colbase + nt * 16 + l15) * D + ks * 32 + lg * 8;
            wh[ks][nt] = *(const bfrag*)(Wth + off);
            wl[ks][nt] = *(const bfrag*)(Wtl + off);
        }

    for (int strip = blockIdx.x * 4 + wave; strip < nStrips; strip += gridDim.x * 4) {
        int row0 = strip * 16;
        bfrag ah[4], al[4];
        #pragma unroll
        for (int ks = 0; ks < 4; ks++)
            unpair(P + (size_t)(row0 + l15) * D + ks * 32 + lg * 8, ah[ks], al[ks]);
        f32x4 acc[NTILES];
        #pragma unroll
        for (int nt = 0; nt < NTILES; nt++) acc[nt] = (f32x4){0.f, 0.f, 0.f, 0.f};
        #pragma unroll
        for (int ks = 0; ks < 4; ks++) {
            #pragma unroll
            for (int nt = 0; nt < NTILES; nt++)
                acc[nt] = __builtin_amdgcn_mfma_f32_16x16x32_bf16(ah[ks], wh[ks][nt], acc[nt], 0, 0, 0);
            #pragma unroll
            for (int nt = 0; nt < NTILES; nt++)
                acc[nt] = __builtin_amdgcn_mfma_f32_16x16x32_bf16(ah[ks], wl[ks][nt], acc[nt], 0, 0, 0);
            #pragma unroll
            for (int nt = 0; nt < NTILES; nt++)
                acc[nt] = __builtin_amdgcn_mfma_f32_16x16x32_bf16(al[ks], wh[ks][nt], acc[nt], 0, 0, 0);
        }
        // C/D layout (m89-verified): col = lane&15, row = (lane>>4)*4 + reg
        #pragma unroll
        for (int nt = 0; nt < NTILES; nt++) {
            int col = colbase + nt * 16 + l15;
            #pragma unroll
            for (int r = 0; r < 4; r++) {
                int row = row0 + lg * 4 + r;
                if (row >= N) continue;
                float v = acc[nt][r];
                if (EPI == 0) {
                    Cf[(size_t)row * D + col] = v;
                } else if (EPI == 1) {
                    Pout[(size_t)row * D + col] = split2p(v + bias[col]);
                } else {
                    if (col < outW) Cf[(size_t)row * outW + col] = v + bias[col];
                }
            }
        }
    }
}

// ---------------- XCD-pinned chunked gather + self-loop + bias + relu -> pair plane ----------------
// chunk = blockIdx.x & 7: with round-robin block->XCD mapping, each XCD streams all edges
// against a 16-col (3.2 MB, L2-resident) slice of t. 4 lanes/node, 64 nodes/block.
__global__ __launch_bounds__(256) void gather_xcd(const int* __restrict__ csr_src, const int* __restrict__ rowbeg,
                                                  const int* __restrict__ deg, const float* __restrict__ dinv,
                                                  const float* __restrict__ t, const float* __restrict__ bias,
                                                  uint32* __restrict__ Pout, int N) {
    int chunk = blockIdx.x & 7;
    int nodeblk = blockIdx.x >> 3;
    int tid = threadIdx.x;
    int nl = tid >> 2;      // 0..63 node within block
    int l4 = tid & 3;       // 4 lanes -> 16 cols
    int node = nodeblk * 64 + nl;
    if (node >= N) return;
    int col0 = chunk * 16 + l4 * 4;
    const float* tc = t + col0;
    int beg = rowbeg[node];
    int end = beg + deg[node];
    float4 a0 = make_float4(0.f, 0.f, 0.f, 0.f);
    float4 a1 = make_float4(0.f, 0.f, 0.f, 0.f);
    int j = beg;
    for (; j + 1 < end; j += 2) {
        int s0 = csr_src[j], s1 = csr_src[j + 1];
        float w0 = dinv[s0], w1 = dinv[s1];
        float4 v0 = *(const float4*)(tc + (size_t)s0 * D);
        float4 v1 = *(const float4*)(tc + (size_t)s1 * D);
        a0.x = fmaf(w0, v0.x, a0.x); a0.y = fmaf(w0, v0.y, a0.y);
        a0.z = fmaf(w0, v0.z, a0.z); a0.w = fmaf(w0, v0.w, a0.w);
        a1.x = fmaf(w1, v1.x, a1.x); a1.y = fmaf(w1, v1.y, a1.y);
        a1.z = fmaf(w1, v1.z, a1.z); a1.w = fmaf(w1, v1.w, a1.w);
    }
    if (j < end) {
        int s0 = csr_src[j];
        float w0 = dinv[s0];
        float4 v0 = *(const float4*)(tc + (size_t)s0 * D);
        a0.x = fmaf(w0, v0.x, a0.x); a0.y = fmaf(w0, v0.y, a0.y);
        a0.z = fmaf(w0, v0.z, a0.z); a0.w = fmaf(w0, v0.w, a0.w);
    }
    a0.x += a1.x; a0.y += a1.y; a0.z += a1.z; a0.w += a1.w;
    float di = dinv[node];
    float sn = di * di;
    float4 tv = *(const float4*)(tc + (size_t)node * D);
    float4 b = *((const float4*)bias + (col0 >> 2));
    float4 r;
    r.x = fmaxf(fmaf(di, a0.x, fmaf(sn, tv.x, b.x)), 0.f);
    r.y = fmaxf(fmaf(di, a0.y, fmaf(sn, tv.y, b.y)), 0.f);
    r.z = fmaxf(fmaf(di, a0.z, fmaf(sn, tv.z, b.z)), 0.f);
    r.w = fmaxf(fmaf(di, a0.w, fmaf(sn, tv.w, b.w)), 0.f);
    uint4 p;
    p.x = split2p(r.x); p.y = split2p(r.y); p.z = split2p(r.z); p.w = split2p(r.w);
    *(uint4*)(Pout + (size_t)node * D + col0) = p;
}

extern "C" void kernel_launch(void* const* d_in, const int* in_sizes, int n_in,
                              void* d_out, int out_size, void* d_ws, size_t ws_size,
                              hipStream_t stream) {
    const float* x      = (const float*)d_in[0];
    const void*  edges  = d_in[1];
    const float* W_pre  = (const float*)d_in[2];
    const float* b_pre  = (const float*)d_in[3];
    const float* W1     = (const float*)d_in[4];
    const float* b1     = (const float*)d_in[5];
    const float* W2     = (const float*)d_in[6];
    const float* b2     = (const float*)d_in[7];
    const float* W_post = (const float*)d_in[8];
    const float* b_post = (const float*)d_in[9];
    float* out = (float*)d_out;

    const int N = in_sizes[0] / D;        // 50000
    const int E = in_sizes[1] / 2;        // 800000
    const int nStrips = (N + 15) / 16;    // 3125
    const int Npad = nStrips * 16;

    // ---- workspace layout (persistent buffers) ----
    char* ws = (char*)d_ws;
    size_t off = 0;
    auto alloc = [&](size_t bytes) { void* p = ws + off; off += (bytes + 255) & ~(size_t)255; return p; };
    uint32* pairA = (uint32*)alloc((size_t)Npad * D * 4);   // pair plane A
    uint32* pairB = (uint32*)alloc((size_t)Npad * D * 4);   // pair plane B
    float*  bufT  = (float*)alloc((size_t)Npad * D * 4);    // fp32 GEMM output t
    float*  dinv   = (float*)alloc((size_t)N * 4);
    int*    deg    = (int*)alloc((size_t)N * 4);
    int*    rowbeg = (int*)alloc((size_t)N * 4);
    int*    csr_src = (int*)alloc((size_t)E * 4);
    unsigned short* wpre_h  = (unsigned short*)alloc(128 * 128 * 2);
    unsigned short* wpre_l  = (unsigned short*)alloc(128 * 128 * 2);
    unsigned short* w1_h    = (unsigned short*)alloc(128 * 128 * 2);
    unsigned short* w1_l    = (unsigned short*)alloc(128 * 128 * 2);
    unsigned short* w2_h    = (unsigned short*)alloc(128 * 128 * 2);
    unsigned short* w2_l    = (unsigned short*)alloc(128 * 128 * 2);
    unsigned short* wpost_h = (unsigned short*)alloc(48 * 128 * 2);
    unsigned short* wpost_l = (unsigned short*)alloc(48 * 128 * 2);

    // ---- prep-phase temporaries OVERLAY bufT (dead before first bufT write) ----
    {
        char* t = (char*)bufT;
        size_t toff = 0;
        auto talloc = [&](size_t bytes) { void* p = t + toff; toff += (bytes + 255) & ~(size_t)255; return p; };
        int* srcdst = (int*)talloc((size_t)2 * E * 4);   // 6.4 MB
        int* cursor = (int*)talloc((size_t)N * 4);
        int* mode2  = (int*)talloc(256);                 // [0]=mode, [1]=counter
        int* src = srcdst;
        int* dst = srcdst + E;
        int* mode = mode2;
        int* counter = mode2 + 1;

        (void)hipMemsetAsync(mode2, 0, 8, stream);
        detect_mode<<<512, 256, 0, stream>>>((const int*)edges, mode, deg, E, N);
        repack_edges<<<(2 * E + 255) / 256, 256, 0, stream>>>(edges, mode, srcdst, 2 * E);
        compute_deg<<<(E + 255) / 256, 256, 0, stream>>>(dst, deg, E);
        node_offsets<<<(N + 255) / 256, 256, 0, stream>>>(deg, dinv, rowbeg, cursor, counter, N);
        fill_csr<<<(E + 255) / 256, 256, 0, stream>>>(src, dst, rowbeg, cursor, csr_src, E);
    }

    // weights: transpose + split, one dispatch
    prep_w_all<<<216, 256, 0, stream>>>(W_pre, W1, W2, W_post,
                                        wpre_h, wpre_l, w1_h, w1_l, w2_h, w2_l, wpost_h, wpost_l);

    // x -> pair plane A
    split_matrix<<<(N * D / 4 + 255) / 256, 256, 0, stream>>>(x, pairA, N * D / 4);

    const int nGatherBlocks = ((N + 63) / 64) * 8;   // 782 node-blocks x 8 XCD chunks
    dim3 g128(391, 2);   // 2 strips/wave, 2 column-halves

    // pre MLP: h1(pairB) = x @ W_pre + b_pre
    gemm_mfma<4, 1><<<g128, 256, 0, stream>>>(pairA, wpre_h, wpre_l, b_pre, nullptr, pairB, nStrips, N, D);

    // conv1: t = h1 @ W1 ; h2(pairA) = relu(gather(t) + b1)
    gemm_mfma<4, 0><<<g128, 256, 0, stream>>>(pairB, w1_h, w1_l, nullptr, bufT, nullptr, nStrips, N, D);
    gather_xcd<<<nGatherBlocks, 256, 0, stream>>>(csr_src, rowbeg, deg, dinv, bufT, b1, pairA, N);

    // conv2: t = h2 @ W2 ; h3(pairB) = relu(gather(t) + b2)
    gemm_mfma<4, 0><<<g128, 256, 0, stream>>>(pairA, w2_h, w2_l, nullptr, bufT, nullptr, nStrips, N, D);
    gather_xcd<<<nGatherBlocks, 256, 0, stream>>>(csr_src, rowbeg, deg, dinv, bufT, b2, pairB, N);

    // post MLP: out = h3 @ W_post + b_post  (40 cols, padded to 48)
    gemm_mfma<3, 2><<<dim3(391, 1), 256, 0, stream>>>(pairB, wpost_h, wpost_l, b_post, out, nullptr, nStrips, N, 40);
}

// Round 7
// 414.561 us; speedup vs baseline: 1.1048x; 1.1048x over previous
//
#include <hip/hip_runtime.h>

#define D 128

typedef short bfrag __attribute__((ext_vector_type(8)));      // 8 bf16 = 4 VGPRs
typedef float f32x4 __attribute__((ext_vector_type(4)));
typedef unsigned uint32;

// ---------------- bf16 split helpers ----------------
__device__ inline unsigned short bf16_rne(float x) {
    unsigned u = __float_as_uint(x);
    return (unsigned short)((u + 0x7FFFu + ((u >> 16) & 1u)) >> 16);
}
__device__ inline float bf16_to_f(unsigned short h) {
    return __uint_as_float(((unsigned)h) << 16);
}
// pair word: hi in bits [15:0], lo in bits [31:16]
__device__ inline unsigned split2p(float x) {
    unsigned short hi = bf16_rne(x);
    unsigned short lo = bf16_rne(x - bf16_to_f(hi));
    return (unsigned)hi | ((unsigned)lo << 16);
}

// unpack 8 pair-words (32B) -> ah (8 hi bf16), al (8 lo bf16)
__device__ inline void unpair(const uint32* __restrict__ p, bfrag& ah, bfrag& al) {
    uint4 q0 = *(const uint4*)p;
    uint4 q1 = *(const uint4*)(p + 4);
    union { uint32 u[4]; bfrag b; } H, L;
    H.u[0] = __builtin_amdgcn_perm(q0.y, q0.x, 0x05040100u);
    H.u[1] = __builtin_amdgcn_perm(q0.w, q0.z, 0x05040100u);
    H.u[2] = __builtin_amdgcn_perm(q1.y, q1.x, 0x05040100u);
    H.u[3] = __builtin_amdgcn_perm(q1.w, q1.z, 0x05040100u);
    L.u[0] = __builtin_amdgcn_perm(q0.y, q0.x, 0x07060302u);
    L.u[1] = __builtin_amdgcn_perm(q0.w, q0.z, 0x07060302u);
    L.u[2] = __builtin_amdgcn_perm(q1.y, q1.x, 0x07060302u);
    L.u[3] = __builtin_amdgcn_perm(q1.w, q1.z, 0x07060302u);
    ah = H.b;
    al = L.b;
}

// ---------------- edge dtype detection (+ deg zero) ----------------
__global__ __launch_bounds__(256) void detect_mode(const int* __restrict__ e, int* __restrict__ mode,
                                                   int* __restrict__ deg, int E, int N) {
    int gid = blockIdx.x * 256 + threadIdx.x;
    int stride = gridDim.x * 256;
    for (int i = gid; i < N; i += stride) deg[i] = 0;
    int found = 0;
    for (int p = gid; p < E; p += stride)
        if (e[2 * p + 1] != 0) found = 1;
    if (found) atomicOr(mode, 1);   // 1 => int32, 0 => int64
}

__global__ __launch_bounds__(256) void repack_edges(const void* __restrict__ eraw, const int* __restrict__ mode,
                                                    int* __restrict__ out, int n2) {
    int i = blockIdx.x * 256 + threadIdx.x;
    if (i >= n2) return;
    int m = *mode;
    out[i] = m ? ((const int*)eraw)[i] : (int)((const long long*)eraw)[i];
}

// ---------------- degree ----------------
__global__ __launch_bounds__(256) void compute_deg(const int* __restrict__ dst, int* __restrict__ deg, int E) {
    int i = blockIdx.x * 256 + threadIdx.x;
    if (i < E) atomicAdd(&deg[dst[i]], 1);
}

// dinv + rowbeg (atomic bump allocator; ordering across nodes irrelevant) + cursor zero
__global__ __launch_bounds__(256) void node_offsets(const int* __restrict__ deg, float* __restrict__ dinv,
                                                    int* __restrict__ rowbeg, int* __restrict__ cursor,
                                                    int* __restrict__ counter, int N) {
    int i = blockIdx.x * 256 + threadIdx.x;
    if (i >= N) return;
    int d = deg[i];
    dinv[i] = 1.0f / sqrtf((float)(d + 1));   // +1 self-loop
    rowbeg[i] = atomicAdd(counter, d);
    cursor[i] = 0;
}

// ---------------- CSR fill (counting sort by dst) ----------------
__global__ __launch_bounds__(256) void fill_csr(const int* __restrict__ src, const int* __restrict__ dst,
                                                const int* __restrict__ rowbeg, int* __restrict__ cursor,
                                                int* __restrict__ csr_src, int E) {
    int e = blockIdx.x * 256 + threadIdx.x;
    if (e >= E) return;
    int d = dst[e];
    int pos = atomicAdd(&cursor[d], 1);
    csr_src[rowbeg[d] + pos] = src[e];
}

// ---------------- fp32 -> pair plane (whole matrix) ----------------
__global__ __launch_bounds__(256) void split_matrix(const float* __restrict__ in, uint32* __restrict__ P, int n4) {
    int i = blockIdx.x * 256 + threadIdx.x;
    if (i >= n4) return;
    float4 v = ((const float4*)in)[i];
    uint4 p;
    p.x = split2p(v.x); p.y = split2p(v.y); p.z = split2p(v.z); p.w = split2p(v.w);
    ((uint4*)P)[i] = p;
}

// ---------------- all weights: transpose + split (4 matrices, one dispatch) ----------------
__global__ __launch_bounds__(256) void prep_w_all(const float* __restrict__ Wpre, const float* __restrict__ W1,
                                                  const float* __restrict__ W2, const float* __restrict__ Wpost,
                                                  unsigned short* __restrict__ preh, unsigned short* __restrict__ prel,
                                                  unsigned short* __restrict__ w1h, unsigned short* __restrict__ w1l,
                                                  unsigned short* __restrict__ w2h, unsigned short* __restrict__ w2l,
                                                  unsigned short* __restrict__ poh, unsigned short* __restrict__ pol) {
    int i = blockIdx.x * 256 + threadIdx.x;
    const float* W; unsigned short *wh, *wl; int idx, ncols;
    if (i < 16384)      { W = Wpre;  wh = preh; wl = prel; idx = i;         ncols = 128; }
    else if (i < 32768) { W = W1;    wh = w1h;  wl = w1l;  idx = i - 16384; ncols = 128; }
    else if (i < 49152) { W = W2;    wh = w2h;  wl = w2l;  idx = i - 32768; ncols = 128; }
    else if (i < 55296) { W = Wpost; wh = poh;  wl = pol;  idx = i - 49152; ncols = 40;  }
    else return;
    int n = idx >> 7, k = idx & 127;
    float v = (n < ncols) ? W[k * ncols + n] : 0.f;
    unsigned p = split2p(v);
    wh[idx] = (unsigned short)p;
    wl[idx] = (unsigned short)(p >> 16);
}

// ---------------- bf16x3 MFMA GEMM (A from pair plane) ----------------
// EPI=0: Cf fp32 CHUNKED layout t_c[chunk][row][16] (chunk = col>>4, stride nStrips*256).
// EPI=1: bias -> pair plane Pout.  EPI=2: bias + fp32 flat, col<outW mask.
template<int NTILES, int EPI>
__global__ __launch_bounds__(256) void gemm_mfma(const uint32* __restrict__ P,
                                                 const unsigned short* __restrict__ Wth,
                                                 const unsigned short* __restrict__ Wtl,
                                                 const float* __restrict__ bias,
                                                 float* __restrict__ Cf,
                                                 uint32* __restrict__ Pout,
                                                 int nStrips, int N, int outW) {
    int wave = threadIdx.x >> 6;
    int lane = threadIdx.x & 63;
    int l15 = lane & 15, lg = lane >> 4;
    int colbase = blockIdx.y * 64;
    size_t chunkStride = (size_t)nStrips * 256;   // Npad*16 floats per 16-col chunk

    // persistent B fragments: wt[col][k] contiguous in k -> 16B per lane
    bfrag wh[4][NTILES], wl[4][NTILES];
    #pragma unroll
    for (int ks = 0; ks < 4; ks++)
        #pragma unroll
        for (int nt = 0; nt < NTILES; nt++) {
            size_t off = (size_t)(colbase + nt * 16 + l15) * D + ks * 32 + lg * 8;
            wh[ks][nt] = *(const bfrag*)(Wth + off);
            wl[ks][nt] = *(const bfrag*)(Wtl + off);
        }

    for (int strip = blockIdx.x * 4 + wave; strip < nStrips; strip += gridDim.x * 4) {
        int row0 = strip * 16;
        bfrag ah[4], al[4];
        #pragma unroll
        for (int ks = 0; ks < 4; ks++)
            unpair(P + (size_t)(row0 + l15) * D + ks * 32 + lg * 8, ah[ks], al[ks]);
        f32x4 acc[NTILES];
        #pragma unroll
        for (int nt = 0; nt < NTILES; nt++) acc[nt] = (f32x4){0.f, 0.f, 0.f, 0.f};
        #pragma unroll
        for (int ks = 0; ks < 4; ks++) {
            #pragma unroll
            for (int nt = 0; nt < NTILES; nt++)
                acc[nt] = __builtin_amdgcn_mfma_f32_16x16x32_bf16(ah[ks], wh[ks][nt], acc[nt], 0, 0, 0);
            #pragma unroll
            for (int nt = 0; nt < NTILES; nt++)
                acc[nt] = __builtin_amdgcn_mfma_f32_16x16x32_bf16(ah[ks], wl[ks][nt], acc[nt], 0, 0, 0);
            #pragma unroll
            for (int nt = 0; nt < NTILES; nt++)
                acc[nt] = __builtin_amdgcn_mfma_f32_16x16x32_bf16(al[ks], wh[ks][nt], acc[nt], 0, 0, 0);
        }
        // C/D layout (m89-verified): col = lane&15, row = (lane>>4)*4 + reg
        #pragma unroll
        for (int nt = 0; nt < NTILES; nt++) {
            int col = colbase + nt * 16 + l15;
            #pragma unroll
            for (int r = 0; r < 4; r++) {
                int row = row0 + lg * 4 + r;
                if (row >= N) continue;
                float v = acc[nt][r];
                if (EPI == 0) {
                    Cf[(size_t)(col >> 4) * chunkStride + (size_t)row * 16 + (col & 15)] = v;
                } else if (EPI == 1) {
                    Pout[(size_t)row * D + col] = split2p(v + bias[col]);
                } else {
                    if (col < outW) Cf[(size_t)row * outW + col] = v + bias[col];
                }
            }
        }
    }
}

// ---------------- XCD-pinned chunked gather (packed slices) + self-loop + bias + relu ----------------
// chunk = blockIdx.x & 7 pins each CONTIGUOUS 3.2MB slice t_c[chunk] to one XCD's L2
// (round-robin block->XCD mapping). Per edge: one 64B contiguous load (4 lanes x float4).
__global__ __launch_bounds__(256) void gather_xcd(const int* __restrict__ csr_src, const int* __restrict__ rowbeg,
                                                  const int* __restrict__ deg, const float* __restrict__ dinv,
                                                  const float* __restrict__ t_c, const float* __restrict__ bias,
                                                  uint32* __restrict__ Pout, int N, int nStrips) {
    int chunk = blockIdx.x & 7;
    int nodeblk = blockIdx.x >> 3;
    int tid = threadIdx.x;
    int nl = tid >> 2;      // 0..63 node within block
    int l4 = tid & 3;       // 4 lanes -> 16 cols
    int node = nodeblk * 64 + nl;
    if (node >= N) return;
    const float* tc = t_c + (size_t)chunk * nStrips * 256 + l4 * 4;   // slice base + lane col
    int beg = rowbeg[node];
    int end = beg + deg[node];
    float4 a0 = make_float4(0.f, 0.f, 0.f, 0.f);
    float4 a1 = make_float4(0.f, 0.f, 0.f, 0.f);
    int j = beg;
    for (; j + 1 < end; j += 2) {
        int s0 = csr_src[j], s1 = csr_src[j + 1];
        float w0 = dinv[s0], w1 = dinv[s1];
        float4 v0 = *(const float4*)(tc + (size_t)s0 * 16);
        float4 v1 = *(const float4*)(tc + (size_t)s1 * 16);
        a0.x = fmaf(w0, v0.x, a0.x); a0.y = fmaf(w0, v0.y, a0.y);
        a0.z = fmaf(w0, v0.z, a0.z); a0.w = fmaf(w0, v0.w, a0.w);
        a1.x = fmaf(w1, v1.x, a1.x); a1.y = fmaf(w1, v1.y, a1.y);
        a1.z = fmaf(w1, v1.z, a1.z); a1.w = fmaf(w1, v1.w, a1.w);
    }
    if (j < end) {
        int s0 = csr_src[j];
        float w0 = dinv[s0];
        float4 v0 = *(const float4*)(tc + (size_t)s0 * 16);
        a0.x = fmaf(w0, v0.x, a0.x); a0.y = fmaf(w0, v0.y, a0.y);
        a0.z = fmaf(w0, v0.z, a0.z); a0.w = fmaf(w0, v0.w, a0.w);
    }
    a0.x += a1.x; a0.y += a1.y; a0.z += a1.z; a0.w += a1.w;
    float di = dinv[node];
    float sn = di * di;
    float4 tv = *(const float4*)(tc + (size_t)node * 16);
    int col0 = chunk * 16 + l4 * 4;
    float4 b = *((const float4*)bias + (col0 >> 2));
    float4 r;
    r.x = fmaxf(fmaf(di, a0.x, fmaf(sn, tv.x, b.x)), 0.f);
    r.y = fmaxf(fmaf(di, a0.y, fmaf(sn, tv.y, b.y)), 0.f);
    r.z = fmaxf(fmaf(di, a0.z, fmaf(sn, tv.z, b.z)), 0.f);
    r.w = fmaxf(fmaf(di, a0.w, fmaf(sn, tv.w, b.w)), 0.f);
    uint4 p;
    p.x = split2p(r.x); p.y = split2p(r.y); p.z = split2p(r.z); p.w = split2p(r.w);
    *(uint4*)(Pout + (size_t)node * D + col0) = p;
}

extern "C" void kernel_launch(void* const* d_in, const int* in_sizes, int n_in,
                              void* d_out, int out_size, void* d_ws, size_t ws_size,
                              hipStream_t stream) {
    const float* x      = (const float*)d_in[0];
    const void*  edges  = d_in[1];
    const float* W_pre  = (const float*)d_in[2];
    const float* b_pre  = (const float*)d_in[3];
    const float* W1     = (const float*)d_in[4];
    const float* b1     = (const float*)d_in[5];
    const float* W2     = (const float*)d_in[6];
    const float* b2     = (const float*)d_in[7];
    const float* W_post = (const float*)d_in[8];
    const float* b_post = (const float*)d_in[9];
    float* out = (float*)d_out;

    const int N = in_sizes[0] / D;        // 50000
    const int E = in_sizes[1] / 2;        // 800000
    const int nStrips = (N + 15) / 16;    // 3125
    const int Npad = nStrips * 16;

    // ---- workspace layout (persistent buffers) ----
    char* ws = (char*)d_ws;
    size_t off = 0;
    auto alloc = [&](size_t bytes) { void* p = ws + off; off += (bytes + 255) & ~(size_t)255; return p; };
    uint32* pairA = (uint32*)alloc((size_t)Npad * D * 4);   // pair plane A
    uint32* pairB = (uint32*)alloc((size_t)Npad * D * 4);   // pair plane B
    float*  bufT  = (float*)alloc((size_t)Npad * D * 4);    // chunked fp32 t_c[8][Npad][16]
    float*  dinv   = (float*)alloc((size_t)N * 4);
    int*    deg    = (int*)alloc((size_t)N * 4);
    int*    rowbeg = (int*)alloc((size_t)N * 4);
    int*    csr_src = (int*)alloc((size_t)E * 4);
    unsigned short* wpre_h  = (unsigned short*)alloc(128 * 128 * 2);
    unsigned short* wpre_l  = (unsigned short*)alloc(128 * 128 * 2);
    unsigned short* w1_h    = (unsigned short*)alloc(128 * 128 * 2);
    unsigned short* w1_l    = (unsigned short*)alloc(128 * 128 * 2);
    unsigned short* w2_h    = (unsigned short*)alloc(128 * 128 * 2);
    unsigned short* w2_l    = (unsigned short*)alloc(128 * 128 * 2);
    unsigned short* wpost_h = (unsigned short*)alloc(48 * 128 * 2);
    unsigned short* wpost_l = (unsigned short*)alloc(48 * 128 * 2);

    // ---- prep-phase temporaries OVERLAY bufT (dead before first bufT write) ----
    {
        char* t = (char*)bufT;
        size_t toff = 0;
        auto talloc = [&](size_t bytes) { void* p = t + toff; toff += (bytes + 255) & ~(size_t)255; return p; };
        int* srcdst = (int*)talloc((size_t)2 * E * 4);   // 6.4 MB
        int* cursor = (int*)talloc((size_t)N * 4);
        int* mode2  = (int*)talloc(256);                 // [0]=mode, [1]=counter
        int* src = srcdst;
        int* dst = srcdst + E;
        int* mode = mode2;
        int* counter = mode2 + 1;

        (void)hipMemsetAsync(mode2, 0, 8, stream);
        detect_mode<<<512, 256, 0, stream>>>((const int*)edges, mode, deg, E, N);
        repack_edges<<<(2 * E + 255) / 256, 256, 0, stream>>>(edges, mode, srcdst, 2 * E);
        compute_deg<<<(E + 255) / 256, 256, 0, stream>>>(dst, deg, E);
        node_offsets<<<(N + 255) / 256, 256, 0, stream>>>(deg, dinv, rowbeg, cursor, counter, N);
        fill_csr<<<(E + 255) / 256, 256, 0, stream>>>(src, dst, rowbeg, cursor, csr_src, E);
    }

    // weights: transpose + split, one dispatch
    prep_w_all<<<216, 256, 0, stream>>>(W_pre, W1, W2, W_post,
                                        wpre_h, wpre_l, w1_h, w1_l, w2_h, w2_l, wpost_h, wpost_l);

    // x -> pair plane A
    split_matrix<<<(N * D / 4 + 255) / 256, 256, 0, stream>>>(x, pairA, N * D / 4);

    const int nGatherBlocks = ((N + 63) / 64) * 8;   // 782 node-blocks x 8 XCD chunks
    dim3 g128(391, 2);   // 2 strips/wave, 2 column-halves

    // pre MLP: h1(pairB) = x @ W_pre + b_pre
    gemm_mfma<4, 1><<<g128, 256, 0, stream>>>(pairA, wpre_h, wpre_l, b_pre, nullptr, pairB, nStrips, N, D);

    // conv1: t_c = h1 @ W1 (chunked) ; h2(pairA) = relu(gather(t_c) + b1)
    gemm_mfma<4, 0><<<g128, 256, 0, stream>>>(pairB, w1_h, w1_l, nullptr, bufT, nullptr, nStrips, N, D);
    gather_xcd<<<nGatherBlocks, 256, 0, stream>>>(csr_src, rowbeg, deg, dinv, bufT, b1, pairA, N, nStrips);

    // conv2: t_c = h2 @ W2 (chunked) ; h3(pairB) = relu(gather(t_c) + b2)
    gemm_mfma<4, 0><<<g128, 256, 0, stream>>>(pairA, w2_h, w2_l, nullptr, bufT, nullptr, nStrips, N, D);
    gather_xcd<<<nGatherBlocks, 256, 0, stream>>>(csr_src, rowbeg, deg, dinv, bufT, b2, pairB, N, nStrips);

    // post MLP: out = h3 @ W_post + b_post  (40 cols, padded to 48)
    gemm_mfma<3, 2><<<dim3(391, 1), 256, 0, stream>>>(pairB, wpost_h, wpost_l, b_post, out, nullptr, nStrips, N, 40);
}

// Round 8
// 370.863 us; speedup vs baseline: 1.2350x; 1.1178x over previous
//
#include <hip/hip_runtime.h>

#define D 128

typedef short bfrag __attribute__((ext_vector_type(8)));      // 8 bf16 = 4 VGPRs
typedef float f32x4 __attribute__((ext_vector_type(4)));
typedef unsigned uint32;

// ---------------- bf16 split helpers ----------------
__device__ inline unsigned short bf16_rne(float x) {
    unsigned u = __float_as_uint(x);
    return (unsigned short)((u + 0x7FFFu + ((u >> 16) & 1u)) >> 16);
}
__device__ inline float bf16_to_f(unsigned short h) {
    return __uint_as_float(((unsigned)h) << 16);
}
// pair word: hi in bits [15:0], lo in bits [31:16]
__device__ inline unsigned split2p(float x) {
    unsigned short hi = bf16_rne(x);
    unsigned short lo = bf16_rne(x - bf16_to_f(hi));
    return (unsigned)hi | ((unsigned)lo << 16);
}

// unpack 8 pair-words (32B) -> ah (8 hi bf16), al (8 lo bf16)
__device__ inline void unpair(const uint32* __restrict__ p, bfrag& ah, bfrag& al) {
    uint4 q0 = *(const uint4*)p;
    uint4 q1 = *(const uint4*)(p + 4);
    union { uint32 u[4]; bfrag b; } H, L;
    H.u[0] = __builtin_amdgcn_perm(q0.y, q0.x, 0x05040100u);
    H.u[1] = __builtin_amdgcn_perm(q0.w, q0.z, 0x05040100u);
    H.u[2] = __builtin_amdgcn_perm(q1.y, q1.x, 0x05040100u);
    H.u[3] = __builtin_amdgcn_perm(q1.w, q1.z, 0x05040100u);
    L.u[0] = __builtin_amdgcn_perm(q0.y, q0.x, 0x07060302u);
    L.u[1] = __builtin_amdgcn_perm(q0.w, q0.z, 0x07060302u);
    L.u[2] = __builtin_amdgcn_perm(q1.y, q1.x, 0x07060302u);
    L.u[3] = __builtin_amdgcn_perm(q1.w, q1.z, 0x07060302u);
    ah = H.b;
    al = L.b;
}

// ---------------- edge dtype detection (+ deg zero) ----------------
__global__ __launch_bounds__(256) void detect_mode(const int* __restrict__ e, int* __restrict__ mode,
                                                   int* __restrict__ deg, int E, int N) {
    int gid = blockIdx.x * 256 + threadIdx.x;
    int stride = gridDim.x * 256;
    for (int i = gid; i < N; i += stride) deg[i] = 0;
    int found = 0;
    for (int p = gid; p < E; p += stride)
        if (e[2 * p + 1] != 0) found = 1;
    if (found) atomicOr(mode, 1);   // 1 => int32, 0 => int64
}

__global__ __launch_bounds__(256) void repack_edges(const void* __restrict__ eraw, const int* __restrict__ mode,
                                                    int* __restrict__ out, int n2) {
    int i = blockIdx.x * 256 + threadIdx.x;
    if (i >= n2) return;
    int m = *mode;
    out[i] = m ? ((const int*)eraw)[i] : (int)((const long long*)eraw)[i];
}

// ---------------- degree ----------------
__global__ __launch_bounds__(256) void compute_deg(const int* __restrict__ dst, int* __restrict__ deg, int E) {
    int i = blockIdx.x * 256 + threadIdx.x;
    if (i < E) atomicAdd(&deg[dst[i]], 1);
}

// dinv + rowbeg (atomic bump allocator; ordering across nodes irrelevant) + cursor zero
__global__ __launch_bounds__(256) void node_offsets(const int* __restrict__ deg, float* __restrict__ dinv,
                                                    int* __restrict__ rowbeg, int* __restrict__ cursor,
                                                    int* __restrict__ counter, int N) {
    int i = blockIdx.x * 256 + threadIdx.x;
    if (i >= N) return;
    int d = deg[i];
    dinv[i] = 1.0f / sqrtf((float)(d + 1));   // +1 self-loop
    rowbeg[i] = atomicAdd(counter, d);
    cursor[i] = 0;
}

// ---------------- CSR fill (counting sort by dst) ----------------
__global__ __launch_bounds__(256) void fill_csr(const int* __restrict__ src, const int* __restrict__ dst,
                                                const int* __restrict__ rowbeg, int* __restrict__ cursor,
                                                int* __restrict__ csr_src, int E) {
    int e = blockIdx.x * 256 + threadIdx.x;
    if (e >= E) return;
    int d = dst[e];
    int pos = atomicAdd(&cursor[d], 1);
    csr_src[rowbeg[d] + pos] = src[e];
}

// ---------------- fp32 -> pair plane (whole matrix) ----------------
__global__ __launch_bounds__(256) void split_matrix(const float* __restrict__ in, uint32* __restrict__ P, int n4) {
    int i = blockIdx.x * 256 + threadIdx.x;
    if (i >= n4) return;
    float4 v = ((const float4*)in)[i];
    uint4 p;
    p.x = split2p(v.x); p.y = split2p(v.y); p.z = split2p(v.z); p.w = split2p(v.w);
    ((uint4*)P)[i] = p;
}

// ---------------- all weights: transpose + split (4 matrices, one dispatch) ----------------
__global__ __launch_bounds__(256) void prep_w_all(const float* __restrict__ Wpre, const float* __restrict__ W1,
                                                  const float* __restrict__ W2, const float* __restrict__ Wpost,
                                                  unsigned short* __restrict__ preh, unsigned short* __restrict__ prel,
                                                  unsigned short* __restrict__ w1h, unsigned short* __restrict__ w1l,
                                                  unsigned short* __restrict__ w2h, unsigned short* __restrict__ w2l,
                                                  unsigned short* __restrict__ poh, unsigned short* __restrict__ pol) {
    int i = blockIdx.x * 256 + threadIdx.x;
    const float* W; unsigned short *wh, *wl; int idx, ncols;
    if (i < 16384)      { W = Wpre;  wh = preh; wl = prel; idx = i;         ncols = 128; }
    else if (i < 32768) { W = W1;    wh = w1h;  wl = w1l;  idx = i - 16384; ncols = 128; }
    else if (i < 49152) { W = W2;    wh = w2h;  wl = w2l;  idx = i - 32768; ncols = 128; }
    else if (i < 55296) { W = Wpost; wh = poh;  wl = pol;  idx = i - 49152; ncols = 40;  }
    else return;
    int n = idx >> 7, k = idx & 127;
    float v = (n < ncols) ? W[k * ncols + n] : 0.f;
    unsigned p = split2p(v);
    wh[idx] = (unsigned short)p;
    wl[idx] = (unsigned short)(p >> 16);
}

// ---------------- bf16x3 MFMA GEMM (A from pair plane) ----------------
// EPI=0: Cf fp32 CHUNKED t'[chunk][row][16] PRE-SCALED by dinv[row] (chunk = col>>4).
// EPI=1: bias -> pair plane Pout.  EPI=2: bias + fp32 flat, col<outW mask.
template<int NTILES, int EPI>
__global__ __launch_bounds__(256) void gemm_mfma(const uint32* __restrict__ P,
                                                 const unsigned short* __restrict__ Wth,
                                                 const unsigned short* __restrict__ Wtl,
                                                 const float* __restrict__ bias,
                                                 const float* __restrict__ dinv,
                                                 float* __restrict__ Cf,
                                                 uint32* __restrict__ Pout,
                                                 int nStrips, int N, int outW) {
    int wave = threadIdx.x >> 6;
    int lane = threadIdx.x & 63;
    int l15 = lane & 15, lg = lane >> 4;
    int colbase = blockIdx.y * 64;
    size_t chunkStride = (size_t)nStrips * 256;   // Npad*16 floats per 16-col chunk

    // persistent B fragments: wt[col][k] contiguous in k -> 16B per lane
    bfrag wh[4][NTILES], wl[4][NTILES];
    #pragma unroll
    for (int ks = 0; ks < 4; ks++)
        #pragma unroll
        for (int nt = 0; nt < NTILES; nt++) {
            size_t off = (size_t)(colbase + nt * 16 + l15) * D + ks * 32 + lg * 8;
            wh[ks][nt] = *(const bfrag*)(Wth + off);
            wl[ks][nt] = *(const bfrag*)(Wtl + off);
        }

    for (int strip = blockIdx.x * 4 + wave; strip < nStrips; strip += gridDim.x * 4) {
        int row0 = strip * 16;
        bfrag ah[4], al[4];
        #pragma unroll
        for (int ks = 0; ks < 4; ks++)
            unpair(P + (size_t)(row0 + l15) * D + ks * 32 + lg * 8, ah[ks], al[ks]);
        f32x4 acc[NTILES];
        #pragma unroll
        for (int nt = 0; nt < NTILES; nt++) acc[nt] = (f32x4){0.f, 0.f, 0.f, 0.f};
        #pragma unroll
        for (int ks = 0; ks < 4; ks++) {
            #pragma unroll
            for (int nt = 0; nt < NTILES; nt++)
                acc[nt] = __builtin_amdgcn_mfma_f32_16x16x32_bf16(ah[ks], wh[ks][nt], acc[nt], 0, 0, 0);
            #pragma unroll
            for (int nt = 0; nt < NTILES; nt++)
                acc[nt] = __builtin_amdgcn_mfma_f32_16x16x32_bf16(ah[ks], wl[ks][nt], acc[nt], 0, 0, 0);
            #pragma unroll
            for (int nt = 0; nt < NTILES; nt++)
                acc[nt] = __builtin_amdgcn_mfma_f32_16x16x32_bf16(al[ks], wh[ks][nt], acc[nt], 0, 0, 0);
        }
        // pre-scale factors for EPI=0 (one per output row this lane covers)
        float dv[4];
        if (EPI == 0) {
            #pragma unroll
            for (int r = 0; r < 4; r++) {
                int row = row0 + lg * 4 + r;
                dv[r] = (row < N) ? dinv[row] : 0.f;
            }
        }
        // C/D layout (m89-verified): col = lane&15, row = (lane>>4)*4 + reg
        #pragma unroll
        for (int nt = 0; nt < NTILES; nt++) {
            int col = colbase + nt * 16 + l15;
            #pragma unroll
            for (int r = 0; r < 4; r++) {
                int row = row0 + lg * 4 + r;
                if (row >= N) continue;
                float v = acc[nt][r];
                if (EPI == 0) {
                    Cf[(size_t)(col >> 4) * chunkStride + (size_t)row * 16 + (col & 15)] = v * dv[r];
                } else if (EPI == 1) {
                    Pout[(size_t)row * D + col] = split2p(v + bias[col]);
                } else {
                    if (col < outW) Cf[(size_t)row * outW + col] = v + bias[col];
                }
            }
        }
    }
}

// ---------------- XCD-pinned chunked gather, edge-way parallel ----------------
// chunk = blockIdx.x & 7 pins a contiguous 3.2MB pre-scaled slice t'[chunk] to one XCD's L2.
// 16 lanes/node: 4 col-lanes x 4 edge-ways; way w walks edges j==w (mod 4), 2-deep unroll
// -> 8 independent loads in flight per node. Combine ways via shfl_xor(4|8).
__global__ __launch_bounds__(256) void gather_xcd(const int* __restrict__ csr_src, const int* __restrict__ rowbeg,
                                                  const int* __restrict__ deg, const float* __restrict__ dinv,
                                                  const float* __restrict__ t_c, const float* __restrict__ bias,
                                                  uint32* __restrict__ Pout, int N, int nStrips) {
    int chunk = blockIdx.x & 7;
    int nodeblk = blockIdx.x >> 3;
    int tid = threadIdx.x;
    int nl = tid >> 4;          // 16 nodes per block
    int w  = (tid >> 2) & 3;    // edge way
    int c  = tid & 3;           // col group (4 cols each)
    int node = nodeblk * 16 + nl;
    if (node >= N) return;
    const float* tc = t_c + (size_t)chunk * nStrips * 256 + c * 4;
    int beg = rowbeg[node];
    int end = beg + deg[node];
    float4 a0 = make_float4(0.f, 0.f, 0.f, 0.f);
    float4 a1 = make_float4(0.f, 0.f, 0.f, 0.f);
    int j = beg + w;
    for (; j + 4 < end; j += 8) {
        int s0 = csr_src[j];
        int s1 = csr_src[j + 4];
        float4 v0 = *(const float4*)(tc + (size_t)s0 * 16);
        float4 v1 = *(const float4*)(tc + (size_t)s1 * 16);
        a0.x += v0.x; a0.y += v0.y; a0.z += v0.z; a0.w += v0.w;
        a1.x += v1.x; a1.y += v1.y; a1.z += v1.z; a1.w += v1.w;
    }
    if (j < end) {
        int s0 = csr_src[j];
        float4 v0 = *(const float4*)(tc + (size_t)s0 * 16);
        a0.x += v0.x; a0.y += v0.y; a0.z += v0.z; a0.w += v0.w;
    }
    a0.x += a1.x; a0.y += a1.y; a0.z += a1.z; a0.w += a1.w;
    // combine the 4 edge-ways (lanes differing in bits 2-3)
    a0.x += __shfl_xor(a0.x, 4); a0.y += __shfl_xor(a0.y, 4);
    a0.z += __shfl_xor(a0.z, 4); a0.w += __shfl_xor(a0.w, 4);
    a0.x += __shfl_xor(a0.x, 8); a0.y += __shfl_xor(a0.y, 8);
    a0.z += __shfl_xor(a0.z, 8); a0.w += __shfl_xor(a0.w, 8);
    if (w != 0) return;
    // t' is pre-scaled by dinv: out = dinv[d]*(sum + t'[d]) + b
    float di = dinv[node];
    float4 tv = *(const float4*)(tc + (size_t)node * 16);
    int col0 = chunk * 16 + c * 4;
    float4 b = *((const float4*)bias + (col0 >> 2));
    float4 r;
    r.x = fmaxf(fmaf(di, a0.x + tv.x, b.x), 0.f);
    r.y = fmaxf(fmaf(di, a0.y + tv.y, b.y), 0.f);
    r.z = fmaxf(fmaf(di, a0.z + tv.z, b.z), 0.f);
    r.w = fmaxf(fmaf(di, a0.w + tv.w, b.w), 0.f);
    uint4 p;
    p.x = split2p(r.x); p.y = split2p(r.y); p.z = split2p(r.z); p.w = split2p(r.w);
    *(uint4*)(Pout + (size_t)node * D + col0) = p;
}

extern "C" void kernel_launch(void* const* d_in, const int* in_sizes, int n_in,
                              void* d_out, int out_size, void* d_ws, size_t ws_size,
                              hipStream_t stream) {
    const float* x      = (const float*)d_in[0];
    const void*  edges  = d_in[1];
    const float* W_pre  = (const float*)d_in[2];
    const float* b_pre  = (const float*)d_in[3];
    const float* W1     = (const float*)d_in[4];
    const float* b1     = (const float*)d_in[5];
    const float* W2     = (const float*)d_in[6];
    const float* b2     = (const float*)d_in[7];
    const float* W_post = (const float*)d_in[8];
    const float* b_post = (const float*)d_in[9];
    float* out = (float*)d_out;

    const int N = in_sizes[0] / D;        // 50000
    const int E = in_sizes[1] / 2;        // 800000
    const int nStrips = (N + 15) / 16;    // 3125
    const int Npad = nStrips * 16;

    // ---- workspace layout (persistent buffers) ----
    char* ws = (char*)d_ws;
    size_t off = 0;
    auto alloc = [&](size_t bytes) { void* p = ws + off; off += (bytes + 255) & ~(size_t)255; return p; };
    uint32* pairA = (uint32*)alloc((size_t)Npad * D * 4);   // pair plane A
    uint32* pairB = (uint32*)alloc((size_t)Npad * D * 4);   // pair plane B
    float*  bufT  = (float*)alloc((size_t)Npad * D * 4);    // chunked pre-scaled t'[8][Npad][16]
    float*  dinv   = (float*)alloc((size_t)N * 4);
    int*    deg    = (int*)alloc((size_t)N * 4);
    int*    rowbeg = (int*)alloc((size_t)N * 4);
    int*    csr_src = (int*)alloc((size_t)E * 4);
    unsigned short* wpre_h  = (unsigned short*)alloc(128 * 128 * 2);
    unsigned short* wpre_l  = (unsigned short*)alloc(128 * 128 * 2);
    unsigned short* w1_h    = (unsigned short*)alloc(128 * 128 * 2);
    unsigned short* w1_l    = (unsigned short*)alloc(128 * 128 * 2);
    unsigned short* w2_h    = (unsigned short*)alloc(128 * 128 * 2);
    unsigned short* w2_l    = (unsigned short*)alloc(128 * 128 * 2);
    unsigned short* wpost_h = (unsigned short*)alloc(48 * 128 * 2);
    unsigned short* wpost_l = (unsigned short*)alloc(48 * 128 * 2);

    // ---- prep-phase temporaries OVERLAY bufT (dead before first bufT write) ----
    {
        char* t = (char*)bufT;
        size_t toff = 0;
        auto talloc = [&](size_t bytes) { void* p = t + toff; toff += (bytes + 255) & ~(size_t)255; return p; };
        int* srcdst = (int*)talloc((size_t)2 * E * 4);   // 6.4 MB
        int* cursor = (int*)talloc((size_t)N * 4);
        int* mode2  = (int*)talloc(256);                 // [0]=mode, [1]=counter
        int* src = srcdst;
        int* dst = srcdst + E;
        int* mode = mode2;
        int* counter = mode2 + 1;

        (void)hipMemsetAsync(mode2, 0, 8, stream);
        detect_mode<<<512, 256, 0, stream>>>((const int*)edges, mode, deg, E, N);
        repack_edges<<<(2 * E + 255) / 256, 256, 0, stream>>>(edges, mode, srcdst, 2 * E);
        compute_deg<<<(E + 255) / 256, 256, 0, stream>>>(dst, deg, E);
        node_offsets<<<(N + 255) / 256, 256, 0, stream>>>(deg, dinv, rowbeg, cursor, counter, N);
        fill_csr<<<(E + 255) / 256, 256, 0, stream>>>(src, dst, rowbeg, cursor, csr_src, E);
    }

    // weights: transpose + split, one dispatch
    prep_w_all<<<216, 256, 0, stream>>>(W_pre, W1, W2, W_post,
                                        wpre_h, wpre_l, w1_h, w1_l, w2_h, w2_l, wpost_h, wpost_l);

    // x -> pair plane A
    split_matrix<<<(N * D / 4 + 255) / 256, 256, 0, stream>>>(x, pairA, N * D / 4);

    const int nGatherBlocks = ((N + 15) / 16) * 8;   // 3125 node-blocks x 8 XCD chunks
    dim3 g128(391, 2);   // 2 strips/wave, 2 column-halves

    // pre MLP: h1(pairB) = x @ W_pre + b_pre
    gemm_mfma<4, 1><<<g128, 256, 0, stream>>>(pairA, wpre_h, wpre_l, b_pre, nullptr, nullptr, pairB, nStrips, N, D);

    // conv1: t' = dinv*(h1 @ W1) (chunked) ; h2(pairA) = relu(dinv*(gather+self) + b1)
    gemm_mfma<4, 0><<<g128, 256, 0, stream>>>(pairB, w1_h, w1_l, nullptr, dinv, bufT, nullptr, nStrips, N, D);
    gather_xcd<<<nGatherBlocks, 256, 0, stream>>>(csr_src, rowbeg, deg, dinv, bufT, b1, pairA, N, nStrips);

    // conv2
    gemm_mfma<4, 0><<<g128, 256, 0, stream>>>(pairA, w2_h, w2_l, nullptr, dinv, bufT, nullptr, nStrips, N, D);
    gather_xcd<<<nGatherBlocks, 256, 0, stream>>>(csr_src, rowbeg, deg, dinv, bufT, b2, pairB, N, nStrips);

    // post MLP: out = h3 @ W_post + b_post  (40 cols, padded to 48)
    gemm_mfma<3, 2><<<dim3(391, 1), 256, 0, stream>>>(pairB, wpost_h, wpost_l, b_post, nullptr, out, nullptr, nStrips, N, 40);
}